// Round 2
// baseline (751.856 us; speedup 1.0000x reference)
//
#include <hip/hip_runtime.h>
#include <stdint.h>

// Problem: VQ codebook argmin. N=2048 queries (C=64) vs K=81920 codes.
// out (f32): [quantized_st 131072][vq_loss][commit_loss][idx 2048]
#define NQ 2048
#define KK 81920
#define CD 64
#define NT 32      // queries per score-block tile
#define KT 256     // codebook entries per block (1 per thread)

#define OUT_VQ 131072
#define OUT_CM 131073
#define OUT_IDX 131074

// ws layout (bytes)
#define WS_KEYS 0        // u64[2048] packed (orderable_score<<32 | k)
#define WS_LOSS 16384    // float accumulator
#define WS_ZN2  16640    // float[2048] numpy-bitwise ||z_n||^2

// Map float to u32 whose unsigned order == float total order.
__device__ __forceinline__ unsigned int f2o(float f) {
  unsigned int u = __float_as_uint(f);
  return (u & 0x80000000u) ? ~u : (u | 0x80000000u);
}

// zn2[n] = np.sum(z[n]*z[n]) replicated BITWISE:
// numpy pairwise_sum n<=128 path: 8 scalar accumulators, squares rounded
// individually (contract off), final tree ((r0+r1)+(r2+r3))+((r4+r5)+(r6+r7)).
// This value sits at ~64 and its ulp (7.6e-6) defines the score quantization
// grid -- it must match numpy exactly or tie-breaks diverge.
__global__ __launch_bounds__(256) void znorm_kernel(const float* __restrict__ z,
                                                    float* __restrict__ zn2) {
#pragma clang fp contract(off)
  const int n = blockIdx.x * 256 + threadIdx.x;
  if (n >= NQ) return;
  const float* a = z + (size_t)n * CD;
  float r[8];
#pragma unroll
  for (int j = 0; j < 8; ++j) { float v = a[j]; r[j] = v * v; }
#pragma unroll
  for (int i = 8; i < CD; i += 8) {
#pragma unroll
    for (int j = 0; j < 8; ++j) { float v = a[i + j]; r[j] += v * v; }
  }
  zn2[n] = ((r[0] + r[1]) + (r[2] + r[3])) + ((r[4] + r[5]) + (r[6] + r[7]));
}

// One thread per codebook entry k; 32 queries staged in LDS.
// score(n,k) = fp32_round(zn2[n] - 2*dot(z_n,e_k))  -- the "+||e||^2" term is
// < half-ulp of the score (|cn|<=9.5e-9 vs >=9.5e-7) so numpy's own +C rounds
// away; we drop it (provably identical under round-to-nearest).
// Dot emulates numpy-einsum npyv kernel: 16 fma accumulators over stride-16
// element chains + halving tree.
__global__ __launch_bounds__(256) void score_kernel(const float* __restrict__ z,
                                                    const float* __restrict__ emb,
                                                    const float* __restrict__ zn2,
                                                    unsigned long long* __restrict__ keys) {
#pragma clang fp contract(off)
  __shared__ float zt[NT * CD];   // 8 KB query tile
  __shared__ float zq[NT];        // bitwise ||z||^2 per query
  const int tid = threadIdx.x;
  const int n0 = blockIdx.x * NT;
  const int k = blockIdx.y * KT + tid;
  const int lane = tid & 63;

  {  // stage z tile: 512 float4, coalesced
    const float4* src = (const float4*)(z + (size_t)n0 * CD);
    float4* dst = (float4*)zt;
    dst[tid]       = src[tid];
    dst[tid + 256] = src[tid + 256];
  }
  if (tid < NT) zq[tid] = zn2[n0 + tid];
  __syncthreads();

  // e-row -> 64 VGPRs
  float e[CD];
  {
    const float4* ep = (const float4*)(emb + (size_t)k * CD);
#pragma unroll
    for (int i = 0; i < 16; ++i) {
      float4 v = ep[i];
      e[4 * i] = v.x; e[4 * i + 1] = v.y; e[4 * i + 2] = v.z; e[4 * i + 3] = v.w;
    }
  }

#pragma unroll 1
  for (int n = 0; n < NT; ++n) {
    const float4* z4 = (const float4*)(zt + n * CD);  // wave-uniform broadcast reads
    float acc[16];
#pragma unroll
    for (int j = 0; j < 16; ++j) acc[j] = 0.0f;
#pragma unroll
    for (int q4 = 0; q4 < 16; ++q4) {
      float4 v = z4[q4];
      const int jb = 4 * (q4 & 3), cb = 4 * q4;
      acc[jb + 0] = __builtin_fmaf(v.x, e[cb + 0], acc[jb + 0]);
      acc[jb + 1] = __builtin_fmaf(v.y, e[cb + 1], acc[jb + 1]);
      acc[jb + 2] = __builtin_fmaf(v.z, e[cb + 2], acc[jb + 2]);
      acc[jb + 3] = __builtin_fmaf(v.w, e[cb + 3], acc[jb + 3]);
    }
    // halving tree (acc[j] holds chain {j, j+16, j+32, j+48})
    float b8[8], b4[4], b2[2];
#pragma unroll
    for (int j = 0; j < 8; ++j) b8[j] = acc[j] + acc[j + 8];
#pragma unroll
    for (int j = 0; j < 4; ++j) b4[j] = b8[j] + b8[j + 4];
    b2[0] = b4[0] + b4[2];
    b2[1] = b4[1] + b4[3];
    const float dot = b2[0] + b2[1];
    // single rounding: 2*dot exact, subtraction rounds once (== numpy A - 2B)
    const float t = zq[n] - 2.0f * dot;
    unsigned long long key = ((unsigned long long)f2o(t) << 32) | (unsigned int)k;
    // wave min-reduce (ties -> lowest k, matching np.argmin first-occurrence)
#pragma unroll
    for (int m = 32; m; m >>= 1) {
      unsigned long long o = __shfl_xor(key, m, 64);
      key = (o < key) ? o : key;
    }
    if (lane == 0) atomicMin(&keys[n0 + n], key);
  }
}

// 4 queries per block: gather winner row, write quantized_st = z + (q - z)
// with numpy's two f32 roundings, idx as float, accumulate sum((z-q)^2).
__global__ __launch_bounds__(256) void finalize_kernel(const float* __restrict__ z,
                                                       const float* __restrict__ emb,
                                                       const unsigned long long* __restrict__ keys,
                                                       float* __restrict__ out,
                                                       float* __restrict__ loss) {
#pragma clang fp contract(off)
  const int t = threadIdx.x;
  const int q = blockIdx.x * 4 + (t >> 6);
  const int c = t & 63;
  const int idx = (int)(keys[q] & 0xFFFFFFFFull);
  const float e = emb[(size_t)idx * CD + c];
  const float zv = z[(size_t)q * CD + c];
  const float dst = e - zv;        // rounds (q - z)
  out[(size_t)q * CD + c] = zv + dst;  // rounds (z + (q-z))
  if (c == 0) out[OUT_IDX + q] = (float)idx;
  float d = zv - e;
  float sq = d * d;
#pragma unroll
  for (int off = 32; off > 0; off >>= 1) sq += __shfl_down(sq, off, 64);
  __shared__ float part[4];
  if (c == 0) part[t >> 6] = sq;
  __syncthreads();
  if (t == 0) atomicAdd(loss, part[0] + part[1] + part[2] + part[3]);
}

__global__ void write_losses(const float* __restrict__ loss, float* __restrict__ out) {
  float m = *loss / (float)(NQ * CD);
  out[OUT_VQ] = m;
  out[OUT_CM] = m;
}

extern "C" void kernel_launch(void* const* d_in, const int* in_sizes, int n_in,
                              void* d_out, int out_size, void* d_ws, size_t ws_size,
                              hipStream_t stream) {
  const float* z = (const float*)d_in[0];
  const float* emb = (const float*)d_in[1];
  float* out = (float*)d_out;
  char* ws = (char*)d_ws;
  unsigned long long* keys = (unsigned long long*)(ws + WS_KEYS);
  float* loss = (float*)(ws + WS_LOSS);
  float* zn2 = (float*)(ws + WS_ZN2);

  hipMemsetAsync(keys, 0xFF, NQ * sizeof(unsigned long long), stream);
  hipMemsetAsync(loss, 0, sizeof(float), stream);

  znorm_kernel<<<NQ / 256, 256, 0, stream>>>(z, zn2);
  score_kernel<<<dim3(NQ / NT, KK / KT), 256, 0, stream>>>(z, emb, zn2, keys);
  finalize_kernel<<<NQ / 4, 256, 0, stream>>>(z, emb, keys, out, loss);
  write_losses<<<1, 1, 0, stream>>>(loss, out);
}

// Round 3
// 395.890 us; speedup vs baseline: 1.8992x; 1.8992x over previous
//
#include <hip/hip_runtime.h>
#include <stdint.h>

// VQ codebook argmin. N=2048 queries (C=64) vs K=81920 codes.
// out (f32): [quantized_st 131072][vq_loss][commit_loss][idx 2048]
#define NQ 2048
#define KK 81920
#define CD 64
#define QPB 256     // queries per block (1 per thread)
#define KSPLIT 160  // k-blocks; each handles KK/KSPLIT = 512 codes
#define KPB (KK / KSPLIT)

#define OUT_VQ 131072
#define OUT_CM 131073
#define OUT_IDX 131074

// ws layout (bytes)
#define WS_KEYS 0        // u64[2048] packed (orderable_score<<32 | k)
#define WS_LOSS 16384    // float accumulator

// Map float to u32 whose unsigned order == float total order.
__device__ __forceinline__ unsigned int f2o(float f) {
  unsigned int u = __float_as_uint(f);
  return (u & 0x80000000u) ? ~u : (u | 0x80000000u);
}

// Transposed-assignment score kernel:
//  - thread owns query n = blockIdx.x*256 + tid; z-row lives in 64 VGPRs
//  - e-rows streamed with WAVE-UNIFORM addresses -> compiler emits s_load
//    (SMEM pipe); v_fma takes the e value as its one SGPR operand.
//  - running (score,k) min kept per-thread; ONE global atomicMin at the end.
// Bitwise-numpy semantics preserved from the passing round-2 kernel:
//  - zn2 = 8-accumulator pairwise pattern, squares rounded (contract off)
//  - dot = 16 fma accumulators over element chains {j,j+16,j+32,j+48} +
//    halving tree; score = single rounding of zn2 - 2*dot ("+||e||^2" term
//    provably below half-ulp, dropped)
//  - lexicographic (score,k) min == np.argmin first-occurrence tie-break
__global__ __launch_bounds__(256) void score_kernel(const float* __restrict__ z,
                                                    const float* __restrict__ emb,
                                                    unsigned long long* __restrict__ keys) {
#pragma clang fp contract(off)
  const int tid = threadIdx.x;
  const int n = blockIdx.x * QPB + tid;
  const int kbase = blockIdx.y * KPB;

  // z-row -> 64 VGPRs (per-lane)
  float zr[CD];
  {
    const float4* zp = (const float4*)(z + (size_t)n * CD);
#pragma unroll
    for (int i = 0; i < 16; ++i) {
      float4 v = zp[i];
      zr[4 * i] = v.x; zr[4 * i + 1] = v.y; zr[4 * i + 2] = v.z; zr[4 * i + 3] = v.w;
    }
  }

  // zn2: numpy pairwise n<=128 path, bitwise (8 accumulators, tree combine)
  float zn2;
  {
    float r[8];
#pragma unroll
    for (int j = 0; j < 8; ++j) r[j] = zr[j] * zr[j];
#pragma unroll
    for (int i = 8; i < CD; i += 8) {
#pragma unroll
      for (int j = 0; j < 8; ++j) r[j] += zr[i + j] * zr[i + j];
    }
    zn2 = ((r[0] + r[1]) + (r[2] + r[3])) + ((r[4] + r[5]) + (r[6] + r[7]));
  }

  unsigned long long best = ~0ull;

#pragma unroll 1
  for (int kk = 0; kk < KPB; ++kk) {
    const int k = kbase + kk;
    const float* er = emb + (size_t)k * CD;  // wave-uniform -> s_load
    float acc[16];
#pragma unroll
    for (int j = 0; j < 16; ++j) acc[j] = 0.0f;
#pragma unroll
    for (int q4 = 0; q4 < 16; ++q4) {
      const int jb = 4 * (q4 & 3), cb = 4 * q4;
      acc[jb + 0] = __builtin_fmaf(er[cb + 0], zr[cb + 0], acc[jb + 0]);
      acc[jb + 1] = __builtin_fmaf(er[cb + 1], zr[cb + 1], acc[jb + 1]);
      acc[jb + 2] = __builtin_fmaf(er[cb + 2], zr[cb + 2], acc[jb + 2]);
      acc[jb + 3] = __builtin_fmaf(er[cb + 3], zr[cb + 3], acc[jb + 3]);
    }
    float b8[8], b4[4];
#pragma unroll
    for (int j = 0; j < 8; ++j) b8[j] = acc[j] + acc[j + 8];
#pragma unroll
    for (int j = 0; j < 4; ++j) b4[j] = b8[j] + b8[j + 4];
    const float dot = (b4[0] + b4[2]) + (b4[1] + b4[3]);
    const float t = zn2 - 2.0f * dot;  // single rounding, == numpy A - 2B
    const unsigned long long key = ((unsigned long long)f2o(t) << 32) | (unsigned int)k;
    best = (key < best) ? key : best;  // lexicographic: ties -> smallest k
  }
  atomicMin(&keys[n], best);
}

// 4 queries per block: gather winner row, write quantized_st = z + (q - z)
// with numpy's two f32 roundings, idx as float, accumulate sum((z-q)^2).
__global__ __launch_bounds__(256) void finalize_kernel(const float* __restrict__ z,
                                                       const float* __restrict__ emb,
                                                       const unsigned long long* __restrict__ keys,
                                                       float* __restrict__ out,
                                                       float* __restrict__ loss) {
#pragma clang fp contract(off)
  const int t = threadIdx.x;
  const int q = blockIdx.x * 4 + (t >> 6);
  const int c = t & 63;
  const int idx = (int)(keys[q] & 0xFFFFFFFFull);
  const float e = emb[(size_t)idx * CD + c];
  const float zv = z[(size_t)q * CD + c];
  const float dst = e - zv;            // rounds (q - z)
  out[(size_t)q * CD + c] = zv + dst;  // rounds (z + (q-z))
  if (c == 0) out[OUT_IDX + q] = (float)idx;
  float d = zv - e;
  float sq = d * d;
#pragma unroll
  for (int off = 32; off > 0; off >>= 1) sq += __shfl_down(sq, off, 64);
  __shared__ float part[4];
  if (c == 0) part[t >> 6] = sq;
  __syncthreads();
  if (t == 0) atomicAdd(loss, part[0] + part[1] + part[2] + part[3]);
}

__global__ void write_losses(const float* __restrict__ loss, float* __restrict__ out) {
  float m = *loss / (float)(NQ * CD);
  out[OUT_VQ] = m;
  out[OUT_CM] = m;
}

extern "C" void kernel_launch(void* const* d_in, const int* in_sizes, int n_in,
                              void* d_out, int out_size, void* d_ws, size_t ws_size,
                              hipStream_t stream) {
  const float* z = (const float*)d_in[0];
  const float* emb = (const float*)d_in[1];
  float* out = (float*)d_out;
  char* ws = (char*)d_ws;
  unsigned long long* keys = (unsigned long long*)(ws + WS_KEYS);
  float* loss = (float*)(ws + WS_LOSS);

  hipMemsetAsync(keys, 0xFF, NQ * sizeof(unsigned long long), stream);
  hipMemsetAsync(loss, 0, sizeof(float), stream);

  score_kernel<<<dim3(NQ / QPB, KSPLIT), 256, 0, stream>>>(z, emb, keys);
  finalize_kernel<<<NQ / 4, 256, 0, stream>>>(z, emb, keys, out, loss);
  write_losses<<<1, 1, 0, stream>>>(loss, out);
}

// Round 5
// 306.806 us; speedup vs baseline: 2.4506x; 1.2904x over previous
//
#include <hip/hip_runtime.h>
#include <stdint.h>

// VQ codebook argmin. N=2048 queries (C=64) vs K=81920 codes.
// out (f32): [quantized_st 131072][vq_loss][commit_loss][idx 2048]
//
// Structure: bf16-MFMA prefilter (2 passes) + exact fp32 rescore.
//  pass1: dot_bf(n,k) via mfma_f32_16x16x32_bf16, per-query global max
//  pass2: same MFMA (bit-identical), collect k with dot_bf >= max - DMARG
//  pass3: exact bitwise-numpy rescore, one WAVE per query; full-scan
//         fallback if candidate list overflowed (statistically never).
// Margin math: numpy winner satisfies dot_bf(k*) >= max_bf - (3.9e-6 + 2*eps),
// eps <= 2^-8*||z||*||e|| <= 4.2e-6  =>  bound 1.23e-5; DMARG=1.6e-5.
// Survivors ~ e^(DMARG/beta), beta = sigma_dot/sqrt(2 ln K) in [6.9e-6,1.2e-5]
// => mean 4-10 per query; CAP=64 => overflow prob ~1e-14..1e-28 per query.
#define NQ 2048
#define KK 81920
#define CD 64
#define CAP 64
#define DMARG 1.6e-5f

#define OUT_VQ 131072
#define OUT_CM 131073
#define OUT_IDX 131074

// ws layout (bytes)
#define WS_QMAX 0        // u32[2048]  f2o(max bf16 dot)   (memset 0)
#define WS_CNT  8192     // int[2048]  candidate counts    (memset 0)
#define WS_KEYS 16384    // u64[2048]  packed (score<<32|k) winners
#define WS_LOSS 32768    // float      loss accumulator
#define WS_CAND 33024    // int[2048*CAP] candidate lists (524288 B)

typedef short v8s __attribute__((ext_vector_type(8)));
typedef float v4f __attribute__((ext_vector_type(4)));

__device__ __forceinline__ unsigned int f2o(float f) {
  unsigned int u = __float_as_uint(f);
  return (u & 0x80000000u) ? ~u : (u | 0x80000000u);
}
__device__ __forceinline__ float o2f(unsigned int u) {
  unsigned int v = (u & 0x80000000u) ? (u & 0x7FFFFFFFu) : ~u;
  return __uint_as_float(v);
}
__device__ __forceinline__ short bf16rne(float f) {
  unsigned int u = __float_as_uint(f);
  u = u + 0x7FFFu + ((u >> 16) & 1u);
  return (short)(u >> 16);
}
__device__ __forceinline__ v8s load_cvt_frag(const float* p) {
  const float4* p4 = (const float4*)p;
  float4 a = p4[0], b = p4[1];
  v8s r;
  r[0] = bf16rne(a.x); r[1] = bf16rne(a.y); r[2] = bf16rne(a.z); r[3] = bf16rne(a.w);
  r[4] = bf16rne(b.x); r[5] = bf16rne(b.y); r[6] = bf16rne(b.z); r[7] = bf16rne(b.w);
  return r;
}

// mfma_f32_16x16x32_bf16 layouts (m89/m91/m120):
//   A: lane holds A[m=lane&15][k=quad*8+j]
//   B: lane holds B[k=quad*8+j][n=lane&15]
//   D: lane,reg r -> D[row=quad*4+r][col=lane&15]
// Block: 256 thr; wave w owns codes [bx*512+w*128, +128) -> 16 resident
// B-frags; loops 16 query-tiles of 32 (by*512 .. +512).
template <bool COLLECT>
__global__ __launch_bounds__(256) void prefilter_kernel(
    const float* __restrict__ z, const float* __restrict__ emb,
    unsigned int* __restrict__ qmax, int* __restrict__ cnt,
    int* __restrict__ cand) {
  const int tid = threadIdx.x;
  const int wave = tid >> 6, lane = tid & 63;
  const int quad = lane >> 4, lrow = lane & 15;
  const int code0 = blockIdx.x * 512 + wave * 128;
  const int q0blk = blockIdx.y * 512;

  v8s B[8][2];
#pragma unroll
  for (int ks = 0; ks < 8; ++ks) {
    const float* er = emb + (size_t)(code0 + ks * 16 + lrow) * CD + quad * 8;
    B[ks][0] = load_cvt_frag(er);
    B[ks][1] = load_cvt_frag(er + 32);
  }

#pragma unroll 1
  for (int qt = 0; qt < 16; ++qt) {
    const int q0 = q0blk + qt * 32;
    v8s A[2][2];
#pragma unroll
    for (int qg = 0; qg < 2; ++qg) {
      const float* zr = z + (size_t)(q0 + qg * 16 + lrow) * CD + quad * 8;
      A[qg][0] = load_cvt_frag(zr);
      A[qg][1] = load_cvt_frag(zr + 32);
    }

    if (!COLLECT) {
      float pmax[2][4];
#pragma unroll
      for (int qg = 0; qg < 2; ++qg)
#pragma unroll
        for (int r = 0; r < 4; ++r) pmax[qg][r] = -1e30f;
#pragma unroll
      for (int ks = 0; ks < 8; ++ks) {
#pragma unroll
        for (int qg = 0; qg < 2; ++qg) {
          v4f acc = {0.f, 0.f, 0.f, 0.f};
          acc = __builtin_amdgcn_mfma_f32_16x16x32_bf16(A[qg][0], B[ks][0], acc, 0, 0, 0);
          acc = __builtin_amdgcn_mfma_f32_16x16x32_bf16(A[qg][1], B[ks][1], acc, 0, 0, 0);
#pragma unroll
          for (int r = 0; r < 4; ++r) pmax[qg][r] = fmaxf(pmax[qg][r], acc[r]);
        }
      }
#pragma unroll
      for (int m = 1; m <= 8; m <<= 1)
#pragma unroll
        for (int qg = 0; qg < 2; ++qg)
#pragma unroll
          for (int r = 0; r < 4; ++r)
            pmax[qg][r] = fmaxf(pmax[qg][r], __shfl_xor(pmax[qg][r], m, 64));
      if (lrow == 0) {
#pragma unroll
        for (int qg = 0; qg < 2; ++qg)
#pragma unroll
          for (int r = 0; r < 4; ++r)
            atomicMax(&qmax[q0 + qg * 16 + quad * 4 + r], f2o(pmax[qg][r]));
      }
    } else {
      float thr[2][4];
#pragma unroll
      for (int qg = 0; qg < 2; ++qg) {
        const uint4 tv = *(const uint4*)(qmax + q0 + qg * 16 + quad * 4);
        thr[qg][0] = o2f(tv.x) - DMARG; thr[qg][1] = o2f(tv.y) - DMARG;
        thr[qg][2] = o2f(tv.z) - DMARG; thr[qg][3] = o2f(tv.w) - DMARG;
      }
#pragma unroll
      for (int ks = 0; ks < 8; ++ks) {
#pragma unroll
        for (int qg = 0; qg < 2; ++qg) {
          v4f acc = {0.f, 0.f, 0.f, 0.f};
          acc = __builtin_amdgcn_mfma_f32_16x16x32_bf16(A[qg][0], B[ks][0], acc, 0, 0, 0);
          acc = __builtin_amdgcn_mfma_f32_16x16x32_bf16(A[qg][1], B[ks][1], acc, 0, 0, 0);
          const float m01 = fmaxf(acc[0] - thr[qg][0], acc[1] - thr[qg][1]);
          const float m23 = fmaxf(acc[2] - thr[qg][2], acc[3] - thr[qg][3]);
          if (fmaxf(m01, m23) >= 0.0f) {
            const int code = code0 + ks * 16 + lrow;
#pragma unroll
            for (int r = 0; r < 4; ++r) {
              if (acc[r] >= thr[qg][r]) {
                const int q = q0 + qg * 16 + quad * 4 + r;
                const int pos = atomicAdd(&cnt[q], 1);
                if (pos < CAP) cand[q * CAP + pos] = code;
              }
            }
          }
        }
      }
    }
  }
}

// Exact bitwise-numpy score of code k against zr/zn2 (round-2/3 verified DAG).
__device__ __forceinline__ unsigned long long exact_key(
    const float* __restrict__ emb, const float zr[CD], float zn2, int k) {
#pragma clang fp contract(off)
  float er[CD];
  const float4* ep = (const float4*)(emb + (size_t)k * CD);
#pragma unroll
  for (int j = 0; j < 16; ++j) {
    float4 v = ep[j];
    er[4 * j] = v.x; er[4 * j + 1] = v.y; er[4 * j + 2] = v.z; er[4 * j + 3] = v.w;
  }
  float acc[16];
#pragma unroll
  for (int j = 0; j < 16; ++j) acc[j] = 0.0f;
#pragma unroll
  for (int q4 = 0; q4 < 16; ++q4) {
    const int jb = 4 * (q4 & 3), cb = 4 * q4;
    acc[jb + 0] = __builtin_fmaf(er[cb + 0], zr[cb + 0], acc[jb + 0]);
    acc[jb + 1] = __builtin_fmaf(er[cb + 1], zr[cb + 1], acc[jb + 1]);
    acc[jb + 2] = __builtin_fmaf(er[cb + 2], zr[cb + 2], acc[jb + 2]);
    acc[jb + 3] = __builtin_fmaf(er[cb + 3], zr[cb + 3], acc[jb + 3]);
  }
  float b8[8], b4[4];
#pragma unroll
  for (int j = 0; j < 8; ++j) b8[j] = acc[j] + acc[j + 8];
#pragma unroll
  for (int j = 0; j < 4; ++j) b4[j] = b8[j] + b8[j + 4];
  const float dot = (b4[0] + b4[2]) + (b4[1] + b4[3]);
  const float t = zn2 - 2.0f * dot;  // single rounding == numpy A - 2B
  return ((unsigned long long)f2o(t) << 32) | (unsigned int)k;
}

// One WAVE per query: lane l rescores candidate slot l; u64 lexicographic
// shuffle-min (ties -> smallest k == np.argmin first-occurrence). If the
// candidate list overflowed (cnt > CAP), exact full scan by this wave.
__global__ __launch_bounds__(256) void rescore_kernel(
    const float* __restrict__ z, const float* __restrict__ emb,
    const int* __restrict__ cnt, const int* __restrict__ cand,
    unsigned long long* __restrict__ keys) {
#pragma clang fp contract(off)
  const int t = threadIdx.x;
  const int wv = t >> 6, lane = t & 63;
  const int n = blockIdx.x * 4 + wv;

  float zr[CD];
  {
    const float4* zp = (const float4*)(z + (size_t)n * CD);  // wave-uniform
#pragma unroll
    for (int i = 0; i < 16; ++i) {
      float4 v = zp[i];
      zr[4 * i] = v.x; zr[4 * i + 1] = v.y; zr[4 * i + 2] = v.z; zr[4 * i + 3] = v.w;
    }
  }
  float zn2;
  {
    float r[8];
#pragma unroll
    for (int j = 0; j < 8; ++j) r[j] = zr[j] * zr[j];
#pragma unroll
    for (int i = 8; i < CD; i += 8)
#pragma unroll
      for (int j = 0; j < 8; ++j) r[j] += zr[i + j] * zr[i + j];
    zn2 = ((r[0] + r[1]) + (r[2] + r[3])) + ((r[4] + r[5]) + (r[6] + r[7]));
  }

  const int c = cnt[n];
  unsigned long long best = ~0ull;
  if (c <= CAP) {
    if (lane < c) best = exact_key(emb, zr, zn2, cand[n * CAP + lane]);
  } else {
    // overflow fallback: exact scan of every code (never fires in practice)
#pragma unroll 1
    for (int k = lane; k < KK; k += 64) {
      unsigned long long key = exact_key(emb, zr, zn2, k);
      best = (key < best) ? key : best;
    }
  }
#pragma unroll
  for (int m = 32; m; m >>= 1) {
    unsigned long long o = __shfl_xor(best, m, 64);
    best = (o < best) ? o : best;
  }
  if (lane == 0) keys[n] = best;
}

// 4 queries per block: quantized_st = z + (q - z) with numpy's two f32
// roundings, idx as float, accumulate sum((z-q)^2).
__global__ __launch_bounds__(256) void finalize_kernel(
    const float* __restrict__ z, const float* __restrict__ emb,
    const unsigned long long* __restrict__ keys, float* __restrict__ out,
    float* __restrict__ loss) {
#pragma clang fp contract(off)
  const int t = threadIdx.x;
  const int q = blockIdx.x * 4 + (t >> 6);
  const int c = t & 63;
  const int idx = (int)(keys[q] & 0xFFFFFFFFull);
  const float e = emb[(size_t)idx * CD + c];
  const float zv = z[(size_t)q * CD + c];
  const float dst = e - zv;
  out[(size_t)q * CD + c] = zv + dst;
  if (c == 0) out[OUT_IDX + q] = (float)idx;
  float d = zv - e;
  float sq = d * d;
#pragma unroll
  for (int off = 32; off > 0; off >>= 1) sq += __shfl_down(sq, off, 64);
  __shared__ float part[4];
  if (c == 0) part[t >> 6] = sq;
  __syncthreads();
  if (t == 0) atomicAdd(loss, part[0] + part[1] + part[2] + part[3]);
}

__global__ void write_losses(const float* __restrict__ loss, float* __restrict__ out) {
  float m = *loss / (float)(NQ * CD);
  out[OUT_VQ] = m;
  out[OUT_CM] = m;
}

extern "C" void kernel_launch(void* const* d_in, const int* in_sizes, int n_in,
                              void* d_out, int out_size, void* d_ws, size_t ws_size,
                              hipStream_t stream) {
  const float* z = (const float*)d_in[0];
  const float* emb = (const float*)d_in[1];
  float* out = (float*)d_out;
  char* ws = (char*)d_ws;
  unsigned int* qmax = (unsigned int*)(ws + WS_QMAX);
  int* cnt = (int*)(ws + WS_CNT);
  unsigned long long* keys = (unsigned long long*)(ws + WS_KEYS);
  float* loss = (float*)(ws + WS_LOSS);
  int* cand = (int*)(ws + WS_CAND);

  hipMemsetAsync(qmax, 0, 2 * NQ * sizeof(int), stream);  // qmax + cnt
  hipMemsetAsync(loss, 0, sizeof(float), stream);

  dim3 grid(KK / 512, NQ / 512);
  prefilter_kernel<false><<<grid, 256, 0, stream>>>(z, emb, qmax, cnt, cand);
  prefilter_kernel<true><<<grid, 256, 0, stream>>>(z, emb, qmax, cnt, cand);
  rescore_kernel<<<NQ / 4, 256, 0, stream>>>(z, emb, cnt, cand, keys);
  finalize_kernel<<<NQ / 4, 256, 0, stream>>>(z, emb, keys, out, loss);
  write_losses<<<1, 1, 0, stream>>>(loss, out);
}

// Round 6
// 235.937 us; speedup vs baseline: 3.1867x; 1.3004x over previous
//
#include <hip/hip_runtime.h>
#include <stdint.h>

// VQ codebook argmin. N=2048 queries (C=64) vs K=81920 codes.
// out (f32): [quantized_st 131072][vq_loss][commit_loss][idx 2048]
//
// Structure: bf16 pre-convert + bf16-MFMA prefilter (2 passes) + exact rescore.
//  conv : z,emb fp32 -> bf16 (rne) into ws (once per launch, ~31 MB traffic)
//  pass1: dot_bf(n,k) via mfma_f32_16x16x32_bf16, per-query global max
//  pass2: bit-identical MFMA, collect k with dot_bf >= max - DMARG
//  pass3: exact bitwise-numpy rescore, one WAVE per query; full-scan
//         fallback if candidate list overflowed (statistically never).
// Margin: numpy winner satisfies dot_bf(k*) >= max_bf - (3.9e-6 + 2*eps),
// eps <= 2^-8*||z||*||e|| <= 4.2e-6 => bound 1.23e-5; DMARG=1.6e-5.
// CAP=64 => overflow prob ~1e-14 per query, plus exact-scan fallback.
#define NQ 2048
#define KK 81920
#define CD 64
#define CAP 64
#define DMARG 1.6e-5f
#define QPB 128              // queries per block (8 groups of 16)

#define OUT_VQ 131072
#define OUT_CM 131073
#define OUT_IDX 131074

// ws layout (bytes)
#define WS_QMAX 0            // u32[2048]  f2o(max bf16 dot)  (memset 0)
#define WS_CNT  8192         // int[2048]  candidate counts   (memset 0)
#define WS_KEYS 16384        // u64[2048]  packed (score<<32|k)
#define WS_LOSS 32768        // float      loss accumulator
#define WS_CAND 33024        // int[2048*CAP]  (524288 B)
#define WS_ZBF  589824       // ushort[131072]   bf16 z      (262144 B)
#define WS_EBF  851968       // ushort[5242880]  bf16 emb    (10485760 B)

typedef short v8s __attribute__((ext_vector_type(8)));
typedef float v4f __attribute__((ext_vector_type(4)));

__device__ __forceinline__ unsigned int f2o(float f) {
  unsigned int u = __float_as_uint(f);
  return (u & 0x80000000u) ? ~u : (u | 0x80000000u);
}
__device__ __forceinline__ float o2f(unsigned int u) {
  unsigned int v = (u & 0x80000000u) ? (u & 0x7FFFFFFFu) : ~u;
  return __uint_as_float(v);
}
__device__ __forceinline__ unsigned int bf16rne(float f) {
  unsigned int u = __float_as_uint(f);
  u = u + 0x7FFFu + ((u >> 16) & 1u);
  return u >> 16;
}

// fp32 -> bf16 for z (32768 float4s) then emb (1310720 float4s), grid-stride.
#define NZ4 32768
#define NTOT4 1343488
__global__ __launch_bounds__(256) void convert_kernel(
    const float* __restrict__ z, const float* __restrict__ emb,
    unsigned int* __restrict__ zbf, unsigned int* __restrict__ ebf) {
  const int stride = gridDim.x * 256;
#pragma unroll 1
  for (int i = blockIdx.x * 256 + threadIdx.x; i < NTOT4; i += stride) {
    const bool isz = (i < NZ4);
    const float4 v = isz ? ((const float4*)z)[i] : ((const float4*)emb)[i - NZ4];
    uint2 o;
    o.x = bf16rne(v.x) | (bf16rne(v.y) << 16);
    o.y = bf16rne(v.z) | (bf16rne(v.w) << 16);
    if (isz) ((uint2*)zbf)[i] = o;
    else     ((uint2*)ebf)[i - NZ4] = o;
  }
}

// mfma_f32_16x16x32_bf16 layouts (m89/m91/m120):
//   A: lane holds A[m=lane&15][k=quad*8+j]
//   B: lane holds B[k=quad*8+j][n=lane&15]
//   D: lane,reg r -> D[row=quad*4+r][col=lane&15]   (row=query, col=code)
// Grid: x = query-block (16 blocks of 128 q, fastest-varying so co-resident
// blocks share one ebf slice in L2), y = code-block (160 blocks of 512).
// Wave w owns codes [by*512 + w*128, +128) -> 16 resident B-frags (64 VGPR);
// loops 8 query-groups of 16.
template <bool COLLECT>
__global__ __launch_bounds__(256) void prefilter_kernel(
    const unsigned short* __restrict__ zbf, const unsigned short* __restrict__ ebf,
    unsigned int* __restrict__ qmax, int* __restrict__ cnt,
    int* __restrict__ cand) {
  const int tid = threadIdx.x;
  const int wave = tid >> 6, lane = tid & 63;
  const int quad = lane >> 4, lrow = lane & 15;
  const int code0 = blockIdx.y * 512 + wave * 128;
  const int q0 = blockIdx.x * QPB;

  // B frags: 8 code-groups x 2 k-halves, one dwordx4 each
  v8s B[8][2];
#pragma unroll
  for (int cg = 0; cg < 8; ++cg) {
    const unsigned short* er = ebf + (size_t)(code0 + cg * 16 + lrow) * CD + quad * 8;
    B[cg][0] = *(const v8s*)er;
    B[cg][1] = *(const v8s*)(er + 32);
  }

#pragma unroll 1
  for (int qg = 0; qg < QPB / 16; ++qg) {
    const unsigned short* zr = zbf + (size_t)(q0 + qg * 16 + lrow) * CD + quad * 8;
    const v8s A0 = *(const v8s*)zr;
    const v8s A1 = *(const v8s*)(zr + 32);

    if (!COLLECT) {
      float pmax[4] = {-1e30f, -1e30f, -1e30f, -1e30f};
#pragma unroll
      for (int cg = 0; cg < 8; ++cg) {
        v4f acc = {0.f, 0.f, 0.f, 0.f};
        acc = __builtin_amdgcn_mfma_f32_16x16x32_bf16(A0, B[cg][0], acc, 0, 0, 0);
        acc = __builtin_amdgcn_mfma_f32_16x16x32_bf16(A1, B[cg][1], acc, 0, 0, 0);
#pragma unroll
        for (int r = 0; r < 4; ++r) pmax[r] = fmaxf(pmax[r], acc[r]);
      }
      // reduce over the 16 lanes (codes) in this quad's lane-group
#pragma unroll
      for (int m = 1; m <= 8; m <<= 1)
#pragma unroll
        for (int r = 0; r < 4; ++r)
          pmax[r] = fmaxf(pmax[r], __shfl_xor(pmax[r], m, 64));
      if (lrow == 0) {
#pragma unroll
        for (int r = 0; r < 4; ++r)
          atomicMax(&qmax[q0 + qg * 16 + quad * 4 + r], f2o(pmax[r]));
      }
    } else {
      const uint4 tv = *(const uint4*)(qmax + q0 + qg * 16 + quad * 4);
      float thr[4];
      thr[0] = o2f(tv.x) - DMARG; thr[1] = o2f(tv.y) - DMARG;
      thr[2] = o2f(tv.z) - DMARG; thr[3] = o2f(tv.w) - DMARG;
#pragma unroll
      for (int cg = 0; cg < 8; ++cg) {
        v4f acc = {0.f, 0.f, 0.f, 0.f};
        acc = __builtin_amdgcn_mfma_f32_16x16x32_bf16(A0, B[cg][0], acc, 0, 0, 0);
        acc = __builtin_amdgcn_mfma_f32_16x16x32_bf16(A1, B[cg][1], acc, 0, 0, 0);
        const float m01 = fmaxf(acc[0] - thr[0], acc[1] - thr[1]);
        const float m23 = fmaxf(acc[2] - thr[2], acc[3] - thr[3]);
        if (fmaxf(m01, m23) >= 0.0f) {  // rare
          const int code = code0 + cg * 16 + lrow;
#pragma unroll
          for (int r = 0; r < 4; ++r) {
            if (acc[r] >= thr[r]) {
              const int q = q0 + qg * 16 + quad * 4 + r;
              const int pos = atomicAdd(&cnt[q], 1);
              if (pos < CAP) cand[q * CAP + pos] = code;
            }
          }
        }
      }
    }
  }
}

// Exact bitwise-numpy score of code k (round-2/3 verified DAG).
__device__ __forceinline__ unsigned long long exact_key(
    const float* __restrict__ emb, const float zr[CD], float zn2, int k) {
#pragma clang fp contract(off)
  float er[CD];
  const float4* ep = (const float4*)(emb + (size_t)k * CD);
#pragma unroll
  for (int j = 0; j < 16; ++j) {
    float4 v = ep[j];
    er[4 * j] = v.x; er[4 * j + 1] = v.y; er[4 * j + 2] = v.z; er[4 * j + 3] = v.w;
  }
  float acc[16];
#pragma unroll
  for (int j = 0; j < 16; ++j) acc[j] = 0.0f;
#pragma unroll
  for (int q4 = 0; q4 < 16; ++q4) {
    const int jb = 4 * (q4 & 3), cb = 4 * q4;
    acc[jb + 0] = __builtin_fmaf(er[cb + 0], zr[cb + 0], acc[jb + 0]);
    acc[jb + 1] = __builtin_fmaf(er[cb + 1], zr[cb + 1], acc[jb + 1]);
    acc[jb + 2] = __builtin_fmaf(er[cb + 2], zr[cb + 2], acc[jb + 2]);
    acc[jb + 3] = __builtin_fmaf(er[cb + 3], zr[cb + 3], acc[jb + 3]);
  }
  float b8[8], b4[4];
#pragma unroll
  for (int j = 0; j < 8; ++j) b8[j] = acc[j] + acc[j + 8];
#pragma unroll
  for (int j = 0; j < 4; ++j) b4[j] = b8[j] + b8[j + 4];
  const float dot = (b4[0] + b4[2]) + (b4[1] + b4[3]);
  const float t = zn2 - 2.0f * dot;  // single rounding == numpy A - 2B
  return ((unsigned long long)f2o(t) << 32) | (unsigned int)k;
}

// One WAVE per query: lane l rescores candidate slot l; u64 lexicographic
// shuffle-min. Overflow (cnt > CAP) -> exact full scan by this wave.
__global__ __launch_bounds__(256) void rescore_kernel(
    const float* __restrict__ z, const float* __restrict__ emb,
    const int* __restrict__ cnt, const int* __restrict__ cand,
    unsigned long long* __restrict__ keys) {
#pragma clang fp contract(off)
  const int t = threadIdx.x;
  const int wv = t >> 6, lane = t & 63;
  const int n = blockIdx.x * 4 + wv;

  float zr[CD];
  {
    const float4* zp = (const float4*)(z + (size_t)n * CD);
#pragma unroll
    for (int i = 0; i < 16; ++i) {
      float4 v = zp[i];
      zr[4 * i] = v.x; zr[4 * i + 1] = v.y; zr[4 * i + 2] = v.z; zr[4 * i + 3] = v.w;
    }
  }
  float zn2;
  {
    float r[8];
#pragma unroll
    for (int j = 0; j < 8; ++j) r[j] = zr[j] * zr[j];
#pragma unroll
    for (int i = 8; i < CD; i += 8)
#pragma unroll
      for (int j = 0; j < 8; ++j) r[j] += zr[i + j] * zr[i + j];
    zn2 = ((r[0] + r[1]) + (r[2] + r[3])) + ((r[4] + r[5]) + (r[6] + r[7]));
  }

  const int c = cnt[n];
  unsigned long long best = ~0ull;
  if (c <= CAP) {
    if (lane < c) best = exact_key(emb, zr, zn2, cand[n * CAP + lane]);
  } else {
#pragma unroll 1
    for (int k = lane; k < KK; k += 64) {
      unsigned long long key = exact_key(emb, zr, zn2, k);
      best = (key < best) ? key : best;
    }
  }
#pragma unroll
  for (int m = 32; m; m >>= 1) {
    unsigned long long o = __shfl_xor(best, m, 64);
    best = (o < best) ? o : best;
  }
  if (lane == 0) keys[n] = best;
}

// 4 queries per block: quantized_st = z + (q - z) with numpy's two f32
// roundings, idx as float, accumulate sum((z-q)^2).
__global__ __launch_bounds__(256) void finalize_kernel(
    const float* __restrict__ z, const float* __restrict__ emb,
    const unsigned long long* __restrict__ keys, float* __restrict__ out,
    float* __restrict__ loss) {
#pragma clang fp contract(off)
  const int t = threadIdx.x;
  const int q = blockIdx.x * 4 + (t >> 6);
  const int c = t & 63;
  const int idx = (int)(keys[q] & 0xFFFFFFFFull);
  const float e = emb[(size_t)idx * CD + c];
  const float zv = z[(size_t)q * CD + c];
  const float dst = e - zv;
  out[(size_t)q * CD + c] = zv + dst;
  if (c == 0) out[OUT_IDX + q] = (float)idx;
  float d = zv - e;
  float sq = d * d;
#pragma unroll
  for (int off = 32; off > 0; off >>= 1) sq += __shfl_down(sq, off, 64);
  __shared__ float part[4];
  if (c == 0) part[t >> 6] = sq;
  __syncthreads();
  if (t == 0) atomicAdd(loss, part[0] + part[1] + part[2] + part[3]);
}

__global__ void write_losses(const float* __restrict__ loss, float* __restrict__ out) {
  float m = *loss / (float)(NQ * CD);
  out[OUT_VQ] = m;
  out[OUT_CM] = m;
}

extern "C" void kernel_launch(void* const* d_in, const int* in_sizes, int n_in,
                              void* d_out, int out_size, void* d_ws, size_t ws_size,
                              hipStream_t stream) {
  const float* z = (const float*)d_in[0];
  const float* emb = (const float*)d_in[1];
  float* out = (float*)d_out;
  char* ws = (char*)d_ws;
  unsigned int* qmax = (unsigned int*)(ws + WS_QMAX);
  int* cnt = (int*)(ws + WS_CNT);
  unsigned long long* keys = (unsigned long long*)(ws + WS_KEYS);
  float* loss = (float*)(ws + WS_LOSS);
  int* cand = (int*)(ws + WS_CAND);
  unsigned int* zbf = (unsigned int*)(ws + WS_ZBF);
  unsigned int* ebf = (unsigned int*)(ws + WS_EBF);

  hipMemsetAsync(qmax, 0, 2 * NQ * sizeof(int), stream);  // qmax + cnt
  hipMemsetAsync(loss, 0, sizeof(float), stream);

  convert_kernel<<<1312, 256, 0, stream>>>(z, emb, zbf, ebf);
  dim3 grid(NQ / QPB, KK / 512);  // x = queries (fast-varying), y = codes
  prefilter_kernel<false><<<grid, 256, 0, stream>>>(
      (const unsigned short*)zbf, (const unsigned short*)ebf, qmax, cnt, cand);
  prefilter_kernel<true><<<grid, 256, 0, stream>>>(
      (const unsigned short*)zbf, (const unsigned short*)ebf, qmax, cnt, cand);
  rescore_kernel<<<NQ / 4, 256, 0, stream>>>(z, emb, cnt, cand, keys);
  finalize_kernel<<<NQ / 4, 256, 0, stream>>>(z, emb, keys, out, loss);
  write_losses<<<1, 1, 0, stream>>>(loss, out);
}